// Round 1
// baseline (239.824 us; speedup 1.0000x reference)
//
#include <hip/hip_runtime.h>
#include <hip/hip_bf16.h>
#include <math.h>

// ---------------------------------------------------------------------------
// SE3 warping field: nerf_encode -> 6-layer MLP (skip@4) -> heads -> se3 exp
// bf16 MFMA for all matmuls; fp32 encode + epilogue.
// ---------------------------------------------------------------------------

typedef __bf16 bf16x8 __attribute__((ext_vector_type(8)));
typedef float  f32x4  __attribute__((ext_vector_type(4)));

#define NROWS 524288
#define BROWS 128

// packed-weight offsets in bf16 elements: [frag f][kstep s][lane][j]
#define P0 0        // L0: K=64  (53 padded),  8 frags * 2 ks * 512
#define P1 8192     // L1: K=128
#define P2 24576
#define P3 40960
#define P4 57344    // L4: K=192 (53+pad11 | 128)
#define P5 81920
#define PH 98304    // head: 1 frag * 4 ks * 512 (cols: v0..2=Wv, 3..5=Wr, rest 0)
#define PTOT 100352

// LDS byte offsets
#define X0_OFF 0        // [128][64 bf16]  stride 128B (encoded input, persistent)
#define XA_OFF 16384    // [128][128 bf16] stride 256B
#define XB_OFF 49152    // [128][128 bf16]
#define SC_OFF 16384    // screw [128][8 f32] (aliases XA; only live after L5)
#define LDS_SZ 81920

// ---------------------------------------------------------------------------
__global__ void pack_w(const float* __restrict__ W0, const float* __restrict__ W1,
                       const float* __restrict__ W2, const float* __restrict__ W3,
                       const float* __restrict__ W4, const float* __restrict__ W5,
                       const float* __restrict__ Wr, const float* __restrict__ Wv,
                       __bf16* __restrict__ pk)
{
    int e = blockIdx.x * 256 + threadIdx.x;
    if (e >= PTOT) return;
    float val = 0.f;
    if (e >= PH) {                                   // head fragment
        int rem = e - PH;
        int s = rem >> 9, r3 = rem & 511, ln = r3 >> 3, j = r3 & 7;
        int col = ln & 15;
        int k = s * 32 + (ln >> 4) * 8 + j;
        if (col < 3)      val = Wv[col * 128 + k];        // v = feat@Wv^T
        else if (col < 6) val = Wr[(col - 3) * 128 + k];  // r = feat@Wr^T
        else              val = 0.f;
    } else {
        const float* W; int KS, base, fan;
        if (e < P1)      { W = W0; KS = 2; base = P0; fan = 53;  }
        else if (e < P2) { W = W1; KS = 4; base = P1; fan = 128; }
        else if (e < P3) { W = W2; KS = 4; base = P2; fan = 128; }
        else if (e < P4) { W = W3; KS = 4; base = P3; fan = 128; }
        else if (e < P5) { W = W4; KS = 6; base = P4; fan = 181; }
        else             { W = W5; KS = 4; base = P5; fan = 128; }
        int rem = e - base;
        int perf = KS * 512;
        int f = rem / perf, r2 = rem % perf;
        int s = r2 >> 9, r3 = r2 & 511, ln = r3 >> 3, j = r3 & 7;
        int col = f * 16 + (ln & 15);
        int k = s * 32 + (ln >> 4) * 8 + j;
        if (fan == 128)     val = W[col * 128 + k];
        else if (fan == 53) val = (k < 53) ? W[col * 53 + k] : 0.f;
        else { // fan 181 padded to 192: [0..52]=inp, [53..63]=0, [64..191]=x
            if (k < 53)      val = W[col * 181 + k];
            else if (k < 64) val = 0.f;
            else             val = W[col * 181 + (k - 11)];
        }
    }
    pk[e] = (__bf16)val;
}

// ---------------------------------------------------------------------------
__global__ __launch_bounds__(256, 2)
void se3_fused(const float* __restrict__ pos, const float* __restrict__ dir,
               const float* __restrict__ wcode,
               const float* __restrict__ b0, const float* __restrict__ b1,
               const float* __restrict__ b2, const float* __restrict__ b3,
               const float* __restrict__ b4, const float* __restrict__ b5,
               const float* __restrict__ br, const float* __restrict__ bv,
               const __bf16* __restrict__ pk,
               float* __restrict__ out)
{
    __shared__ unsigned char smem[LDS_SZ];
    const int tid  = threadIdx.x;
    const int lane = tid & 63;
    const int cl   = lane & 15;    // row-in-frag (A) / col-in-frag (B, C/D)
    const int gp   = lane >> 4;    // lane group 0..3
    const int wid  = tid >> 6;
    const int r0   = blockIdx.x * BROWS;

    // ---------------- encode: X0[row][64] = [sin21 | cos21 | p3 | wc8 | 0*11]
    {
        int row = tid >> 1, h = tid & 1;
        int g = r0 + row;
        float p3[3] = { pos[g*3+0], pos[g*3+1], pos[g*3+2] };
        unsigned char* base = smem + X0_OFF + row * 128;
        int sw = (row & 7) << 4;
        auto put = [&](int col, float v) {
            *(__bf16*)(base + ((col * 2) ^ sw)) = (__bf16)v;
        };
        if (h == 0) {
            #pragma unroll
            for (int a = 0; a < 3; a++)
                #pragma unroll
                for (int f = 0; f < 4; f++) {
                    float t = p3[a] * (float)(1 << f);
                    t -= floorf(t);
                    float ang = 6.283185307179586f * t;
                    put(a*7+f,      __sinf(ang));
                    put(21+a*7+f,   __cosf(ang));
                }
        } else {
            #pragma unroll
            for (int a = 0; a < 3; a++)
                #pragma unroll
                for (int f = 4; f < 7; f++) {
                    float t = p3[a] * (float)(1 << f);
                    t -= floorf(t);
                    float ang = 6.283185307179586f * t;
                    put(a*7+f,      __sinf(ang));
                    put(21+a*7+f,   __cosf(ang));
                }
            put(42, p3[0]); put(43, p3[1]); put(44, p3[2]);
            #pragma unroll
            for (int j = 0; j < 8; j++) put(45+j, wcode[g*8+j]);
            #pragma unroll
            for (int c = 53; c < 64; c++) put(c, 0.f);
        }
    }
    __syncthreads();

    // ---------------- generic MLP layer (col-split across 4 waves) ----------
    // wave computes cols [wid*32, wid*32+32) for all 128 rows.
    auto layer = [&](int KS, int splitS, int inOff, int inStride,
                     int pkOff, const float* bias, int outOff) {
        f32x4 acc[8][2];
        float bb0 = bias[wid*32 + cl];
        float bb1 = bias[wid*32 + 16 + cl];
        #pragma unroll
        for (int rf = 0; rf < 8; rf++) {
            acc[rf][0] = f32x4{bb0, bb0, bb0, bb0};
            acc[rf][1] = f32x4{bb1, bb1, bb1, bb1};
        }
        const bf16x8* pB = (const bf16x8*)(pk + pkOff);
        for (int s = 0; s < KS; s++) {
            bf16x8 Bf0 = pB[((wid*2)     * KS + s) * 64 + lane];
            bf16x8 Bf1 = pB[((wid*2 + 1) * KS + s) * 64 + lane];
            int bbase, bstride, kloc;
            if (s < splitS) { bbase = X0_OFF; bstride = 128;      kloc = s * 32; }
            else            { bbase = inOff;  bstride = inStride; kloc = (s - splitS) * 32; }
            int kb = kloc * 2 + gp * 16;
            #pragma unroll
            for (int rf = 0; rf < 8; rf++) {
                int row = rf * 16 + cl;
                bf16x8 A = *(const bf16x8*)(smem + bbase + row * bstride
                                            + (kb ^ ((row & 7) << 4)));
                acc[rf][0] = __builtin_amdgcn_mfma_f32_16x16x32_bf16(A, Bf0, acc[rf][0], 0, 0, 0);
                acc[rf][1] = __builtin_amdgcn_mfma_f32_16x16x32_bf16(A, Bf1, acc[rf][1], 0, 0, 0);
            }
        }
        // ReLU + bf16 store (D layout: col=lane&15, row=(lane>>4)*4+reg)
        #pragma unroll
        for (int rf = 0; rf < 8; rf++)
            #pragma unroll
            for (int cf = 0; cf < 2; cf++) {
                int cb = ((wid*2 + cf) * 16 + cl) * 2;
                #pragma unroll
                for (int r = 0; r < 4; r++) {
                    int row = rf * 16 + gp * 4 + r;
                    float v = acc[rf][cf][r];
                    v = v > 0.f ? v : 0.f;
                    *(__bf16*)(smem + outOff + row * 256 + (cb ^ ((row & 7) << 4))) = (__bf16)v;
                }
            }
        __syncthreads();
    };

    layer(2, 0, X0_OFF, 128, P0, b0, XA_OFF);
    layer(4, 0, XA_OFF, 256, P1, b1, XB_OFF);
    layer(4, 0, XB_OFF, 256, P2, b2, XA_OFF);
    layer(4, 0, XA_OFF, 256, P3, b3, XB_OFF);
    layer(6, 2, XB_OFF, 256, P4, b4, XA_OFF);   // skip: s<2 from X0, rest from XB
    layer(4, 0, XA_OFF, 256, P5, b5, XB_OFF);

    // ---------------- heads via one MFMA fragment: screw=[v(3), r(3)] -------
    // row-split: wave w does row-fragments {2w, 2w+1}.
    {
        f32x4 ha[2];
        float hb = (cl < 3) ? bv[cl] : ((cl < 6) ? br[cl - 3] : 0.f);
        ha[0] = f32x4{hb, hb, hb, hb};
        ha[1] = f32x4{hb, hb, hb, hb};
        const bf16x8* pB = (const bf16x8*)(pk + PH);
        #pragma unroll
        for (int s = 0; s < 4; s++) {
            bf16x8 Bf = pB[s * 64 + lane];
            int kb = s * 64 + gp * 16;
            #pragma unroll
            for (int q = 0; q < 2; q++) {
                int row = (wid*2 + q) * 16 + cl;
                bf16x8 A = *(const bf16x8*)(smem + XB_OFF + row * 256
                                            + (kb ^ ((row & 7) << 4)));
                ha[q] = __builtin_amdgcn_mfma_f32_16x16x32_bf16(A, Bf, ha[q], 0, 0, 0);
            }
        }
        if (cl < 6) {
            #pragma unroll
            for (int q = 0; q < 2; q++)
                #pragma unroll
                for (int r = 0; r < 4; r++) {
                    int row = (wid*2 + q) * 16 + gp * 4 + r;
                    *(float*)(smem + SC_OFF + row * 32 + cl * 4) = ha[q][r];
                }
        }
    }
    __syncthreads();

    // ---------------- se3 exp map epilogue (fp32, 1 thread per row) ---------
    if (tid < BROWS) {
        int row = tid, g = r0 + row;
        const float* sc = (const float*)(smem + SC_OFF + row * 32);
        float v0 = sc[0], v1 = sc[1], v2 = sc[2];
        float wx = sc[3], wy = sc[4], wz = sc[5];
        float ang2 = wx*wx + wy*wy + wz*wz;
        ang2 = fmaxf(ang2, 1e-4f);               // jnp.clip(.., eps)
        float ang = sqrtf(ang2);
        float sn = __sinf(ang), cs = __cosf(ang);
        float f1 = sn / ang;
        float f2 = (1.f - cs) / ang2;
        float f3 = (ang - sn) / (ang * ang2);
        // K = [[0, z, -y], [-z, 0, x], [y, -x, 0]]  (reference's _hat_pt3d)
        float K[3][3] = {{0.f,  wz, -wy}, {-wz, 0.f,  wx}, { wy, -wx, 0.f}};
        float KK[3][3];
        #pragma unroll
        for (int i = 0; i < 3; i++)
            #pragma unroll
            for (int j = 0; j < 3; j++)
                KK[i][j] = K[i][0]*K[0][j] + K[i][1]*K[1][j] + K[i][2]*K[2][j];
        float R[3][3], V[3][3];
        #pragma unroll
        for (int i = 0; i < 3; i++)
            #pragma unroll
            for (int j = 0; j < 3; j++) {
                float id = (i == j) ? 1.f : 0.f;
                R[i][j] = id + f1 * K[i][j] + f2 * KK[i][j];
                V[i][j] = id + f2 * K[i][j] + f3 * KK[i][j];
            }
        float T0 = V[0][0]*v0 + V[0][1]*v1 + V[0][2]*v2;
        float T1 = V[1][0]*v0 + V[1][1]*v1 + V[1][2]*v2;
        float T2 = V[2][0]*v0 + V[2][1]*v1 + V[2][2]*v2;
        float px = pos[g*3+0], py = pos[g*3+1], pz = pos[g*3+2];
        float dx = dir[g*3+0], dy = dir[g*3+1], dz = dir[g*3+2];
        // M_rot = R^T : wp[i] = sum_j R[j][i]*p[j] + T[i]
        float wpx = R[0][0]*px + R[1][0]*py + R[2][0]*pz + T0;
        float wpy = R[0][1]*px + R[1][1]*py + R[2][1]*pz + T1;
        float wpz = R[0][2]*px + R[1][2]*py + R[2][2]*pz + T2;
        float wdx = R[0][0]*dx + R[1][0]*dy + R[2][0]*dz;
        float wdy = R[0][1]*dx + R[1][1]*dy + R[2][1]*dz;
        float wdz = R[0][2]*dx + R[1][2]*dy + R[2][2]*dz;
        wpx = (wpx != wpx) ? px : wpx;
        wpy = (wpy != wpy) ? py : wpy;
        wpz = (wpz != wpz) ? pz : wpz;
        wdx = (wdx != wdx) ? dx : wdx;
        wdy = (wdy != wdy) ? dy : wdy;
        wdz = (wdz != wdz) ? dz : wdz;
        out[g*3+0] = wpx; out[g*3+1] = wpy; out[g*3+2] = wpz;
        float* o2 = out + (size_t)NROWS * 3;
        o2[g*3+0] = wdx; o2[g*3+1] = wdy; o2[g*3+2] = wdz;
    }
}

// ---------------------------------------------------------------------------
extern "C" void kernel_launch(void* const* d_in, const int* in_sizes, int n_in,
                              void* d_out, int out_size, void* d_ws, size_t ws_size,
                              hipStream_t stream)
{
    const float* pos = (const float*)d_in[0];
    const float* dir = (const float*)d_in[1];
    const float* wc  = (const float*)d_in[2];
    const float* W0 = (const float*)d_in[3];  const float* b0 = (const float*)d_in[4];
    const float* W1 = (const float*)d_in[5];  const float* b1 = (const float*)d_in[6];
    const float* W2 = (const float*)d_in[7];  const float* b2 = (const float*)d_in[8];
    const float* W3 = (const float*)d_in[9];  const float* b3 = (const float*)d_in[10];
    const float* W4 = (const float*)d_in[11]; const float* b4 = (const float*)d_in[12];
    const float* W5 = (const float*)d_in[13]; const float* b5 = (const float*)d_in[14];
    const float* Wr = (const float*)d_in[15]; const float* br = (const float*)d_in[16];
    const float* Wv = (const float*)d_in[17]; const float* bv = (const float*)d_in[18];
    __bf16* pk = (__bf16*)d_ws;
    float* out = (float*)d_out;

    pack_w<<<(PTOT + 255) / 256, 256, 0, stream>>>(W0, W1, W2, W3, W4, W5, Wr, Wv, pk);
    se3_fused<<<NROWS / BROWS, 256, 0, stream>>>(pos, dir, wc,
                                                 b0, b1, b2, b3, b4, b5,
                                                 br, bv, pk, out);
}

// Round 2
// 221.920 us; speedup vs baseline: 1.0807x; 1.0807x over previous
//
#include <hip/hip_runtime.h>
#include <hip/hip_bf16.h>
#include <math.h>

// ---------------------------------------------------------------------------
// SE3 warping field: nerf_encode -> 6-layer MLP (skip@4) -> heads -> se3 exp
// Round 2: swapped MFMA (Y^T = W * X^T), single LDS activation buffer,
// vectorized b64 activation stores, 2-stage K-step register pipeline.
// ---------------------------------------------------------------------------

typedef __bf16 bf16x8 __attribute__((ext_vector_type(8)));
typedef float  f32x4  __attribute__((ext_vector_type(4)));

#define NROWS 524288
#define BROWS 128

// packed-weight offsets in bf16 elements: [frag f][kstep s][lane][j]
// frag f = out-col group (A-fragment rows m = 16f + (lane&15)),
// k = 32s + 8*(lane>>4) + j   -- identical layout to round 1 (verified).
#define P0 0        // L0: K=64  (53 padded)
#define P1 8192     // L1: K=128
#define P2 24576
#define P3 40960
#define P4 57344    // L4: K=192 (53+pad11 | 128)
#define P5 81920
#define PH 98304    // head: m 0..2=Wv rows, 3..5=Wr rows, rest 0
#define PTOT 100352

// LDS byte offsets
#define X0_OFF 0        // [128][64 bf16]  stride 128B (encoded input; dead after L4)
#define XA_OFF 16384    // [128][128 bf16] stride 256B (in-place activations)
#define SC_OFF 0        // screw [128][8 f32] (aliases X0; written at head phase)
#define LDS_SZ 49152

// ---------------------------------------------------------------------------
__global__ void pack_w(const float* __restrict__ W0, const float* __restrict__ W1,
                       const float* __restrict__ W2, const float* __restrict__ W3,
                       const float* __restrict__ W4, const float* __restrict__ W5,
                       const float* __restrict__ Wr, const float* __restrict__ Wv,
                       __bf16* __restrict__ pk)
{
    int e = blockIdx.x * 256 + threadIdx.x;
    if (e >= PTOT) return;
    float val = 0.f;
    if (e >= PH) {                                   // head fragment
        int rem = e - PH;
        int s = rem >> 9, r3 = rem & 511, ln = r3 >> 3, j = r3 & 7;
        int col = ln & 15;
        int k = s * 32 + (ln >> 4) * 8 + j;
        if (col < 3)      val = Wv[col * 128 + k];        // v = feat@Wv^T
        else if (col < 6) val = Wr[(col - 3) * 128 + k];  // r = feat@Wr^T
        else              val = 0.f;
    } else {
        const float* W; int KS, base, fan;
        if (e < P1)      { W = W0; KS = 2; base = P0; fan = 53;  }
        else if (e < P2) { W = W1; KS = 4; base = P1; fan = 128; }
        else if (e < P3) { W = W2; KS = 4; base = P2; fan = 128; }
        else if (e < P4) { W = W3; KS = 4; base = P3; fan = 128; }
        else if (e < P5) { W = W4; KS = 6; base = P4; fan = 181; }
        else             { W = W5; KS = 4; base = P5; fan = 128; }
        int rem = e - base;
        int perf = KS * 512;
        int f = rem / perf, r2 = rem % perf;
        int s = r2 >> 9, r3 = r2 & 511, ln = r3 >> 3, j = r3 & 7;
        int col = f * 16 + (ln & 15);
        int k = s * 32 + (ln >> 4) * 8 + j;
        if (fan == 128)     val = W[col * 128 + k];
        else if (fan == 53) val = (k < 53) ? W[col * 53 + k] : 0.f;
        else { // fan 181 padded to 192: [0..52]=inp, [53..63]=0, [64..191]=x
            if (k < 53)      val = W[col * 181 + k];
            else if (k < 64) val = 0.f;
            else             val = W[col * 181 + (k - 11)];
        }
    }
    pk[e] = (__bf16)val;
}

// ---------------------------------------------------------------------------
__device__ __forceinline__ unsigned pack_bf16_2(float a, float b) {
    union { __bf16 h; unsigned short u; } x, y;
    x.h = (__bf16)a; y.h = (__bf16)b;
    return ((unsigned)y.u << 16) | (unsigned)x.u;
}

// One MLP layer, swapped scheme. Wave (mfG,nfG) of 2x2:
//   owns out-cols m in [64*mfG, 64*mfG+64), batch rows [64*nfG, 64*nfG+64).
// acc[mf][nf] D-layout: lane(cl,gp) holds D[m=64mfG+16mf+4gp+r][n=64nfG+16nf+cl].
template<int KS, int SPLITS>
__device__ __forceinline__ void mlp_layer(unsigned char* smem,
    const __bf16* __restrict__ pkL, const float* __restrict__ bias,
    int inOff, int inStride, int outOff,
    int lane, int cl, int gp, int mfG, int nfG)
{
    const bf16x8* pW = (const bf16x8*)pkL;

    f32x4 acc[4][4];
    #pragma unroll
    for (int mf = 0; mf < 4; mf++) {
        f32x4 bb = *(const f32x4*)(bias + mfG * 64 + mf * 16 + gp * 4);
        #pragma unroll
        for (int nf = 0; nf < 4; nf++) acc[mf][nf] = bb;   // bias pre-loaded into acc
    }

    bf16x8 Wf[2][4], Bf[2][4];
    auto loadW = [&](bf16x8* dst, int s) {
        #pragma unroll
        for (int mf = 0; mf < 4; mf++)
            dst[mf] = pW[((mfG * 4 + mf) * KS + s) * 64 + lane];
    };
    auto loadB = [&](bf16x8* dst, int s) {
        int base, stride, k0;
        if (s < SPLITS) { base = X0_OFF; stride = 128;      k0 = s * 32; }
        else            { base = inOff;  stride = inStride; k0 = (s - SPLITS) * 32; }
        int bc = 2 * k0 + 16 * gp;
        #pragma unroll
        for (int nf = 0; nf < 4; nf++) {
            int row = nfG * 64 + nf * 16 + cl;
            dst[nf] = *(const bf16x8*)(smem + base + row * stride
                                       + (bc ^ ((row & 7) << 4)));
        }
    };

    loadW(Wf[0], 0);
    loadB(Bf[0], 0);
    #pragma unroll
    for (int s = 0; s < KS; s++) {
        if (s + 1 < KS) { loadW(Wf[(s + 1) & 1], s + 1); loadB(Bf[(s + 1) & 1], s + 1); }
        #pragma unroll
        for (int mf = 0; mf < 4; mf++)
            #pragma unroll
            for (int nf = 0; nf < 4; nf++)
                acc[mf][nf] = __builtin_amdgcn_mfma_f32_16x16x32_bf16(
                    Wf[s & 1][mf], Bf[s & 1][nf], acc[mf][nf], 0, 0, 0);
    }

    __syncthreads();   // all reads of the in-place buffer done
    #pragma unroll
    for (int mf = 0; mf < 4; mf++)
        #pragma unroll
        for (int nf = 0; nf < 4; nf++) {
            int row = nfG * 64 + nf * 16 + cl;
            int bc  = 128 * mfG + 32 * mf + 8 * gp;
            f32x4 a = acc[mf][nf];
            uint2 w;
            w.x = pack_bf16_2(fmaxf(a[0], 0.f), fmaxf(a[1], 0.f));
            w.y = pack_bf16_2(fmaxf(a[2], 0.f), fmaxf(a[3], 0.f));
            *(uint2*)(smem + outOff + row * 256 + (bc ^ ((row & 7) << 4))) = w;
        }
    __syncthreads();
}

// ---------------------------------------------------------------------------
__global__ __launch_bounds__(256, 3)
void se3_fused(const float* __restrict__ pos, const float* __restrict__ dir,
               const float* __restrict__ wcode,
               const float* __restrict__ b0, const float* __restrict__ b1,
               const float* __restrict__ b2, const float* __restrict__ b3,
               const float* __restrict__ b4, const float* __restrict__ b5,
               const float* __restrict__ br, const float* __restrict__ bv,
               const __bf16* __restrict__ pk,
               float* __restrict__ out)
{
    __shared__ unsigned char smem[LDS_SZ];
    const int tid  = threadIdx.x;
    const int lane = tid & 63;
    const int cl   = lane & 15;
    const int gp   = lane >> 4;
    const int wid  = tid >> 6;
    const int mfG  = wid & 1;
    const int nfG  = wid >> 1;
    const int r0   = blockIdx.x * BROWS;

    // ---------------- encode: X0[row][64] = [sin21 | cos21 | p3 | wc8 | 0*11]
    {
        int row = tid >> 1, h = tid & 1;
        int g = r0 + row;
        float p3[3] = { pos[g*3+0], pos[g*3+1], pos[g*3+2] };
        unsigned char* base = smem + X0_OFF + row * 128;
        int sw = (row & 7) << 4;
        auto put = [&](int col, float v) {
            *(__bf16*)(base + ((col * 2) ^ sw)) = (__bf16)v;
        };
        if (h == 0) {
            #pragma unroll
            for (int a = 0; a < 3; a++)
                #pragma unroll
                for (int f = 0; f < 4; f++) {
                    float t = p3[a] * (float)(1 << f);
                    t -= floorf(t);
                    float ang = 6.283185307179586f * t;
                    put(a*7+f,      __sinf(ang));
                    put(21+a*7+f,   __cosf(ang));
                }
        } else {
            #pragma unroll
            for (int a = 0; a < 3; a++)
                #pragma unroll
                for (int f = 4; f < 7; f++) {
                    float t = p3[a] * (float)(1 << f);
                    t -= floorf(t);
                    float ang = 6.283185307179586f * t;
                    put(a*7+f,      __sinf(ang));
                    put(21+a*7+f,   __cosf(ang));
                }
            put(42, p3[0]); put(43, p3[1]); put(44, p3[2]);
            #pragma unroll
            for (int j = 0; j < 8; j++) put(45+j, wcode[g*8+j]);
            #pragma unroll
            for (int c = 53; c < 64; c++) put(c, 0.f);
        }
    }
    __syncthreads();

    // ---------------- MLP stem (in-place single buffer XA) ------------------
    mlp_layer<2,0>(smem, pk + P0, b0, X0_OFF, 128, XA_OFF, lane, cl, gp, mfG, nfG);
    mlp_layer<4,0>(smem, pk + P1, b1, XA_OFF, 256, XA_OFF, lane, cl, gp, mfG, nfG);
    mlp_layer<4,0>(smem, pk + P2, b2, XA_OFF, 256, XA_OFF, lane, cl, gp, mfG, nfG);
    mlp_layer<4,0>(smem, pk + P3, b3, XA_OFF, 256, XA_OFF, lane, cl, gp, mfG, nfG);
    mlp_layer<6,2>(smem, pk + P4, b4, XA_OFF, 256, XA_OFF, lane, cl, gp, mfG, nfG); // skip: s<2 from X0
    mlp_layer<4,0>(smem, pk + P5, b5, XA_OFF, 256, XA_OFF, lane, cl, gp, mfG, nfG);

    // ---------------- heads: screw = [v(3) | r(3)] (mfG==0 waves only) ------
    if (mfG == 0) {
        const bf16x8* pW = (const bf16x8*)(pk + PH);
        f32x4 hb;
        #pragma unroll
        for (int r = 0; r < 4; r++) {
            int m = gp * 4 + r;
            hb[r] = (m < 3) ? bv[m] : ((m < 6) ? br[m - 3] : 0.f);
        }
        f32x4 hacc[4];
        #pragma unroll
        for (int nf = 0; nf < 4; nf++) hacc[nf] = hb;
        #pragma unroll
        for (int s = 0; s < 4; s++) {
            bf16x8 Wh = pW[s * 64 + lane];
            int bc = 64 * s + 16 * gp;
            #pragma unroll
            for (int nf = 0; nf < 4; nf++) {
                int row = nfG * 64 + nf * 16 + cl;
                bf16x8 B = *(const bf16x8*)(smem + XA_OFF + row * 256
                                            + (bc ^ ((row & 7) << 4)));
                hacc[nf] = __builtin_amdgcn_mfma_f32_16x16x32_bf16(Wh, B, hacc[nf], 0, 0, 0);
            }
        }
        // screw store: lane(cl,gp) holds m=4gp+r for batch row nfG*64+nf*16+cl
        #pragma unroll
        for (int nf = 0; nf < 4; nf++) {
            int row = nfG * 64 + nf * 16 + cl;
            if (gp == 0) {
                *(f32x4*)(smem + SC_OFF + row * 32) = hacc[nf];     // m 0..3
            } else if (gp == 1) {
                *(float*)(smem + SC_OFF + row * 32 + 16) = hacc[nf][0]; // m 4
                *(float*)(smem + SC_OFF + row * 32 + 20) = hacc[nf][1]; // m 5
            }
        }
    }
    __syncthreads();

    // ---------------- se3 exp map epilogue (fp32, 1 thread per row) ---------
    if (tid < BROWS) {
        int row = tid, g = r0 + row;
        const float* sc = (const float*)(smem + SC_OFF + row * 32);
        float v0 = sc[0], v1 = sc[1], v2 = sc[2];
        float wx = sc[3], wy = sc[4], wz = sc[5];
        float ang2 = wx*wx + wy*wy + wz*wz;
        ang2 = fmaxf(ang2, 1e-4f);               // jnp.clip(.., eps)
        float ang = sqrtf(ang2);
        float sn = __sinf(ang), cs = __cosf(ang);
        float f1 = sn / ang;
        float f2 = (1.f - cs) / ang2;
        float f3 = (ang - sn) / (ang * ang2);
        float K[3][3] = {{0.f,  wz, -wy}, {-wz, 0.f,  wx}, { wy, -wx, 0.f}};
        float KK[3][3];
        #pragma unroll
        for (int i = 0; i < 3; i++)
            #pragma unroll
            for (int j = 0; j < 3; j++)
                KK[i][j] = K[i][0]*K[0][j] + K[i][1]*K[1][j] + K[i][2]*K[2][j];
        float R[3][3], V[3][3];
        #pragma unroll
        for (int i = 0; i < 3; i++)
            #pragma unroll
            for (int j = 0; j < 3; j++) {
                float id = (i == j) ? 1.f : 0.f;
                R[i][j] = id + f1 * K[i][j] + f2 * KK[i][j];
                V[i][j] = id + f2 * K[i][j] + f3 * KK[i][j];
            }
        float T0 = V[0][0]*v0 + V[0][1]*v1 + V[0][2]*v2;
        float T1 = V[1][0]*v0 + V[1][1]*v1 + V[1][2]*v2;
        float T2 = V[2][0]*v0 + V[2][1]*v1 + V[2][2]*v2;
        float px = pos[g*3+0], py = pos[g*3+1], pz = pos[g*3+2];
        float dx = dir[g*3+0], dy = dir[g*3+1], dz = dir[g*3+2];
        // M_rot = R^T : wp[i] = sum_j R[j][i]*p[j] + T[i]
        float wpx = R[0][0]*px + R[1][0]*py + R[2][0]*pz + T0;
        float wpy = R[0][1]*px + R[1][1]*py + R[2][1]*pz + T1;
        float wpz = R[0][2]*px + R[1][2]*py + R[2][2]*pz + T2;
        float wdx = R[0][0]*dx + R[1][0]*dy + R[2][0]*dz;
        float wdy = R[0][1]*dx + R[1][1]*dy + R[2][1]*dz;
        float wdz = R[0][2]*dx + R[1][2]*dy + R[2][2]*dz;
        wpx = (wpx != wpx) ? px : wpx;
        wpy = (wpy != wpy) ? py : wpy;
        wpz = (wpz != wpz) ? pz : wpz;
        wdx = (wdx != wdx) ? dx : wdx;
        wdy = (wdy != wdy) ? dy : wdy;
        wdz = (wdz != wdz) ? dz : wdz;
        out[g*3+0] = wpx; out[g*3+1] = wpy; out[g*3+2] = wpz;
        float* o2 = out + (size_t)NROWS * 3;
        o2[g*3+0] = wdx; o2[g*3+1] = wdy; o2[g*3+2] = wdz;
    }
}

// ---------------------------------------------------------------------------
extern "C" void kernel_launch(void* const* d_in, const int* in_sizes, int n_in,
                              void* d_out, int out_size, void* d_ws, size_t ws_size,
                              hipStream_t stream)
{
    const float* pos = (const float*)d_in[0];
    const float* dir = (const float*)d_in[1];
    const float* wc  = (const float*)d_in[2];
    const float* W0 = (const float*)d_in[3];  const float* b0 = (const float*)d_in[4];
    const float* W1 = (const float*)d_in[5];  const float* b1 = (const float*)d_in[6];
    const float* W2 = (const float*)d_in[7];  const float* b2 = (const float*)d_in[8];
    const float* W3 = (const float*)d_in[9];  const float* b3 = (const float*)d_in[10];
    const float* W4 = (const float*)d_in[11]; const float* b4 = (const float*)d_in[12];
    const float* W5 = (const float*)d_in[13]; const float* b5 = (const float*)d_in[14];
    const float* Wr = (const float*)d_in[15]; const float* br = (const float*)d_in[16];
    const float* Wv = (const float*)d_in[17]; const float* bv = (const float*)d_in[18];
    __bf16* pk = (__bf16*)d_ws;
    float* out = (float*)d_out;

    pack_w<<<(PTOT + 255) / 256, 256, 0, stream>>>(W0, W1, W2, W3, W4, W5, Wr, Wv, pk);
    se3_fused<<<NROWS / BROWS, 256, 0, stream>>>(pos, dir, wc,
                                                 b0, b1, b2, b3, b4, b5,
                                                 br, bv, pk, out);
}